// Round 1
// baseline (59.174 us; speedup 1.0000x reference)
//
#include <hip/hip_runtime.h>
#include <hip/hip_bf16.h>

#define L_CLS 2048
#define D_DIM 512
#define B_SZ  64
#define T_SZ  512
#define NT    511           // T-1 transitions per sequence
#define NOUT  (B_SZ * NT)   // 32704

typedef __attribute__((ext_vector_type(8))) short bf16x8;
typedef __attribute__((ext_vector_type(4))) float f32x4;

static __device__ __forceinline__ float bits2f(unsigned short u) {
    union { unsigned int i; float f; } v; v.i = ((unsigned int)u) << 16; return v.f;
}

// ---------------------------------------------------------------- conv kernel
// f32 -> bf16 for both tables (L*D elements each) into workspace.
__global__ void conv_bf16(const float* __restrict__ srcE, const float* __restrict__ tgtE,
                          __hip_bfloat16* __restrict__ Sb, __hip_bfloat16* __restrict__ Tb) {
    int i = blockIdx.x * blockDim.x + threadIdx.x;
    if (i < L_CLS * D_DIM) {
        Sb[i] = __float2bfloat16(srcE[i]);
        Tb[i] = __float2bfloat16(tgtE[i]);
    }
}

// ------------------------------------------------------- fused GEMM + row-LSE
// grid (32, 8): blockIdx.x = 64-row block of S, blockIdx.y = 256-col chunk of T.
// 256 threads = 4 waves; wave w owns rows [bx*64 + w*16, +16).
// Each wave: hoist A frags (16 k-steps), then per 16-col tile run 16 MFMAs and
// fold the 16x16 logits tile into per-lane online (max,sum).
__launch_bounds__(256)
__global__ void lse_partial(const __hip_bfloat16* __restrict__ Sb,
                            const __hip_bfloat16* __restrict__ Tb,
                            float* __restrict__ pmax, float* __restrict__ psum) {
    const int wave = threadIdx.x >> 6;
    const int lane = threadIdx.x & 63;
    const int R = blockIdx.x * 64 + wave * 16;   // source-row base of this wave
    const int C = blockIdx.y * 256;              // target-col chunk base
    const int lr = lane & 15;                    // row (A) / col (B) within 16
    const int lk = (lane >> 4) * 8;              // k offset within the K=32 step

    // A fragments for all 16 k-steps (rows R+lr, 8 contiguous k-elems each)
    bf16x8 a[16];
    const __hip_bfloat16* arow = Sb + (R + lr) * D_DIM + lk;
#pragma unroll
    for (int ks = 0; ks < 16; ++ks)
        a[ks] = *reinterpret_cast<const bf16x8*>(arow + ks * 32);

    float m[4] = {-INFINITY, -INFINITY, -INFINITY, -INFINITY};
    float s[4] = {0.f, 0.f, 0.f, 0.f};

    for (int ct = 0; ct < 16; ++ct) {
        const __hip_bfloat16* brow = Tb + (C + ct * 16 + lr) * D_DIM + lk;
        f32x4 acc = {0.f, 0.f, 0.f, 0.f};
#pragma unroll
        for (int ks = 0; ks < 16; ++ks) {
            bf16x8 b = *reinterpret_cast<const bf16x8*>(brow + ks * 32);
            acc = __builtin_amdgcn_mfma_f32_16x16x32_bf16(a[ks], b, acc, 0, 0, 0);
        }
        // D layout: col = lane&15, row = (lane>>4)*4 + i  ->  lane covers 4 rows,
        // 1 col of this tile. Online (max,sum) update per row.
#pragma unroll
        for (int i = 0; i < 4; ++i) {
            float x  = acc[i];
            float mn = fmaxf(m[i], x);
            s[i] = s[i] * __expf(m[i] - mn) + __expf(x - mn);
            m[i] = mn;
        }
    }

    // Reduce (max,sum) across the 16 lanes that share rows (same lane>>4 group).
#pragma unroll
    for (int off = 1; off < 16; off <<= 1) {
#pragma unroll
        for (int i = 0; i < 4; ++i) {
            float om = __shfl_xor(m[i], off);
            float os = __shfl_xor(s[i], off);
            float mn = fmaxf(m[i], om);
            s[i] = s[i] * __expf(m[i] - mn) + os * __expf(om - mn);
            m[i] = mn;
        }
    }

    if (lr == 0) {
        int g = lane >> 4;
#pragma unroll
        for (int i = 0; i < 4; ++i) {
            int row = R + g * 4 + i;
            pmax[row * 8 + blockIdx.y] = m[i];
            psum[row * 8 + blockIdx.y] = s[i];
        }
    }
}

// ------------------------------------------------------------ combine chunks
__global__ void lse_final(const float* __restrict__ pmax, const float* __restrict__ psum,
                          float* __restrict__ lse) {
    int row = blockIdx.x * blockDim.x + threadIdx.x;
    if (row < L_CLS) {
        float m = -INFINITY, s = 0.f;
#pragma unroll
        for (int c = 0; c < 8; ++c) {
            float pm = pmax[row * 8 + c], ps = psum[row * 8 + c];
            float mn = fmaxf(m, pm);
            s = s * __expf(m - mn) + ps * __expf(pm - mn);
            m = mn;
        }
        lse[row] = m + __logf(s);
    }
}

// --------------------------------------------------------------- gather-dots
// one wave per output element: scores[b,t] = dot(Sb[src], Tb[tgt]) - lse[src]
__launch_bounds__(256)
__global__ void scores_kernel(const int* __restrict__ labels,
                              const __hip_bfloat16* __restrict__ Sb,
                              const __hip_bfloat16* __restrict__ Tb,
                              const float* __restrict__ lse,
                              float* __restrict__ out) {
    const int wid  = blockIdx.x * 4 + (threadIdx.x >> 6);   // grid sized exactly
    const int lane = threadIdx.x & 63;
    const int b = wid / NT;
    const int t = wid - b * NT;
    const int src = labels[b * T_SZ + t];
    const int tgt = labels[b * T_SZ + t + 1];

    bf16x8 sv = *reinterpret_cast<const bf16x8*>(Sb + src * D_DIM + lane * 8);
    bf16x8 tv = *reinterpret_cast<const bf16x8*>(Tb + tgt * D_DIM + lane * 8);
    float acc = 0.f;
#pragma unroll
    for (int j = 0; j < 8; ++j)
        acc += bits2f((unsigned short)sv[j]) * bits2f((unsigned short)tv[j]);

#pragma unroll
    for (int off = 32; off; off >>= 1)
        acc += __shfl_xor(acc, off);

    if (lane == 0) out[wid] = acc - lse[src];
}

// ------------------------------------------------------------------- launcher
extern "C" void kernel_launch(void* const* d_in, const int* in_sizes, int n_in,
                              void* d_out, int out_size, void* d_ws, size_t ws_size,
                              hipStream_t stream) {
    const int*   labels = (const int*)d_in[0];
    const float* srcE   = (const float*)d_in[1];
    const float* tgtE   = (const float*)d_in[2];
    float*       out    = (float*)d_out;

    char* ws = (char*)d_ws;
    __hip_bfloat16* Sb = (__hip_bfloat16*)ws;                       // 2 MB
    __hip_bfloat16* Tb = Sb + L_CLS * D_DIM;                        // 2 MB
    float* pmax = (float*)(ws + (size_t)2 * L_CLS * D_DIM * 2);     // 64 KB
    float* psum = pmax + L_CLS * 8;                                 // 64 KB
    float* lse  = psum + L_CLS * 8;                                 // 8 KB

    conv_bf16<<<(L_CLS * D_DIM + 255) / 256, 256, 0, stream>>>(srcE, tgtE, Sb, Tb);
    lse_partial<<<dim3(32, 8), 256, 0, stream>>>(Sb, Tb, pmax, psum);
    lse_final<<<(L_CLS + 255) / 256, 256, 0, stream>>>(pmax, psum, lse);
    scores_kernel<<<NOUT / 4, 256, 0, stream>>>(labels, Sb, Tb, lse, out);
}